// Round 1
// baseline (211.158 us; speedup 1.0000x reference)
//
#include <hip/hip_runtime.h>
#include <stdint.h>

// Self-attention: x[4,2048,768] fp32, W_q/W_k/W_v [768,768] fp32 -> out[4,2048,768] fp32.
//
// v7: proj + S-GEMM moved to a 256x256 8-wave quad-buffered BK=32 core with the
// 8-phase schedule (T3+T4+T5): raw s_barrier (no vmcnt drain), counted
// s_waitcnt vmcnt(8) at tile boundaries (loads stay 3 tiles in flight),
// setprio(1) around each 16-MFMA cluster. Packed fragment layout retained
// (it already gives near-floor b128 LDS reads, playing T2's role).
// PV kept as the 128^2 4-wave kernel (384 blocks fill the device; a 96-block
// 256^2 PV would idle 60% of CUs). S-GEMM grid is exactly 256 blocks (1/CU).
//
// Packed layout: operand = [row-block r/128][it = k/64][16 KB chunk]; chunk =
// [p = k-octet 0..8][r 0..128][8 u16]; granule addr: block*(NIT*8192) + it*8192
// + p*1024 + r*8 + e.  A 32-k tile = half-chunk (octets 4h..4h+3).

typedef unsigned short u16;
typedef unsigned int u32;

typedef __attribute__((ext_vector_type(4))) float f32x4;
typedef __attribute__((ext_vector_type(8))) __bf16 bf16x8;
typedef __attribute__((ext_vector_type(8))) short s16x8;
typedef __attribute__((ext_vector_type(8))) unsigned short us16x8;

template <class T> T&& declv();
template <typename T, typename V = void>
struct mfma_ok { static constexpr bool value = false; };
template <typename T>
struct mfma_ok<T, decltype((void)__builtin_amdgcn_mfma_f32_16x16x32_bf16(
                     declv<T>(), declv<T>(), declv<f32x4>(), 0, 0, 0))> {
  static constexpr bool value = true;
};
template <bool BF, bool S16> struct pick_frag { typedef us16x8 type; };
template <bool S16> struct pick_frag<true, S16> { typedef bf16x8 type; };
template <> struct pick_frag<false, true> { typedef s16x8 type; };
typedef typename pick_frag<mfma_ok<bf16x8>::value, mfma_ok<s16x8>::value>::type frag_t;

__device__ inline f32x4 mfma16x16x32(frag_t a, frag_t b, f32x4 c) {
  return __builtin_amdgcn_mfma_f32_16x16x32_bf16(a, b, c, 0, 0, 0);
}

#define AS3(p) ((__attribute__((address_space(3))) void*)(p))
#define AS1c(p) ((__attribute__((address_space(1))) void*)(const void*)(p))

__device__ inline u16 f2bf(float f) {
  union { float f; u32 u; } v; v.f = f;
  u32 r = v.u + 0x7fffu + ((v.u >> 16) & 1u);  // RNE
  return (u16)(r >> 16);
}

#define GR 8192        // u16 per it-chunk (16 KB)
#define BOFF4 8192     // u16 offset of B half of LDS (128^2 loop)

// =====================================================================
// Old 128x128 / 4-wave loop — kept for gemm_pv only.
// =====================================================================
__device__ inline void gemm_loop4(u16* smem, const u16* __restrict__ Ap,
                                  const u16* __restrict__ Bp, int nit,
                                  f32x4 acc[4][4])
{
  const int tid  = threadIdx.x;
  const int lane = tid & 63;
  const int wave = tid >> 6;
  const int quad = lane >> 4;
  const int l16  = lane & 15;
  const int wm   = (wave & 1) * 64;
  const int wn   = (wave >> 1) * 64;
  const int so   = wave * 2048;
  const int lo   = lane << 3;

#pragma unroll
  for (int i = 0; i < 4; i++)
#pragma unroll
    for (int j = 0; j < 4; j++) acc[i][j] = f32x4{0.f, 0.f, 0.f, 0.f};

  for (int it = 0; it < nit; ++it) {
    const long o = (long)it * GR;
    __syncthreads();
#pragma unroll
    for (int j = 0; j < 4; j++) {
      __builtin_amdgcn_global_load_lds(AS1c(Ap + o + so + j * 512 + lo),
                                       AS3(smem + so + j * 512), 16, 0, 0);
      __builtin_amdgcn_global_load_lds(AS1c(Bp + o + so + j * 512 + lo),
                                       AS3(smem + BOFF4 + so + j * 512), 16, 0, 0);
    }
    __syncthreads();

#pragma unroll
    for (int s = 0; s < 2; s++) {
      frag_t af[4], bf_[4];
#pragma unroll
      for (int mt = 0; mt < 4; mt++)
        af[mt] = *(const frag_t*)(&smem[(s * 4 + quad) * 1024 + (wm + mt * 16 + l16) * 8]);
#pragma unroll
      for (int nt = 0; nt < 4; nt++)
        bf_[nt] = *(const frag_t*)(&smem[BOFF4 + (s * 4 + quad) * 1024 + (wn + nt * 16 + l16) * 8]);
#pragma unroll
      for (int mt = 0; mt < 4; mt++)
#pragma unroll
        for (int nt = 0; nt < 4; nt++)
          acc[mt][nt] = mfma16x16x32(af[mt], bf_[nt], acc[mt][nt]);
    }
  }
}

// =====================================================================
// New 256x256 / 8-wave / BK=32 / quad-buffered core.
// LDS: 4 buffers x 16384 u16; buffer = [A0 4096][A1 4096][B0 4096][B1 4096],
// each sub = [oct 0..3][row 0..127][8 u16]  (== half of a packed it-chunk).
// Tile t: it = t>>1, half = t&1 -> global piece offset (t>>1)*8192+(t&1)*4096.
// Waves: 2M x 4N; per-wave output 128x64 (M_rep=8, N_rep=4).
// Per tile: 2 phases x {ds_read subtile, stage 2 pieces of tile t+3,
//   barrier, lgkmcnt(0), setprio(1), 16 MFMA, setprio(0), barrier};
// counted vmcnt(8) at tile boundary (tiles t+2,t+3 stay in flight).
// Race-free: tile T+3's loads target buf[(T+3)&3] == buf[(T-1)&3], whose last
// reader finished before the end-of-(T-1) barrier, which precedes any issue.
// =====================================================================
__device__ __forceinline__ void gemm256_loop(u16* smem,
    const u16* __restrict__ A0, const u16* __restrict__ A1,
    const u16* __restrict__ B0, const u16* __restrict__ B1,
    int nt32, f32x4 acc[8][4])
{
  const int tid   = threadIdx.x;
  const int lane  = tid & 63;
  const int wave  = tid >> 6;      // 0..7
  const int quad  = lane >> 4;
  const int l16   = lane & 15;
  const int waveM = wave >> 2;     // 0..1
  const int waveN = wave & 3;      // 0..3
  const int wch   = wave * 512;    // staging chunk (u16) within an 8 KB piece
  const int lo    = lane * 8;      // u16

#pragma unroll
  for (int i = 0; i < 8; i++)
#pragma unroll
    for (int j = 0; j < 4; j++) acc[i][j] = f32x4{0.f, 0.f, 0.f, 0.f};

#define STAGE2(PA, PB, T, PBASE) do {                                          \
    const long _o = ((long)((T) >> 1) << 13) + (long)(((T) & 1) << 12);        \
    const int _db = (((T) & 3) << 14) + ((PBASE) << 12) + wch;                 \
    __builtin_amdgcn_global_load_lds(AS1c((PA) + _o + wch + lo),               \
                                     AS3(smem + _db), 16, 0, 0);               \
    __builtin_amdgcn_global_load_lds(AS1c((PB) + _o + wch + lo),               \
                                     AS3(smem + _db + 4096), 16, 0, 0);        \
  } while (0)

  // Prologue: stage tiles 0,1,2 (12 loads/thread); wait until tile 0 landed.
  STAGE2(A0, A1, 0, 0); STAGE2(B0, B1, 0, 2);
  STAGE2(A0, A1, 1, 0); STAGE2(B0, B1, 1, 2);
  STAGE2(A0, A1, 2, 0); STAGE2(B0, B1, 2, 2);
  asm volatile("s_waitcnt vmcnt(8)" ::: "memory");
  __builtin_amdgcn_s_barrier();

  for (int t = 0; t < nt32; ++t) {
    const int bb = (t & 3) << 14;
    const int aB = bb + (waveM << 12) + quad * 1024 + l16 * 8;
    const int bB = bb + 8192 + ((waveN >> 1) << 12) + quad * 1024
                 + ((waveN & 1) * 64 + l16) * 8;
    frag_t af[4], bfr[4];

    // ---- phase 0 (row-half 0) ----
#pragma unroll
    for (int nt = 0; nt < 4; nt++) bfr[nt] = *(const frag_t*)(smem + bB + nt * 128);
#pragma unroll
    for (int mt = 0; mt < 4; mt++) af[mt] = *(const frag_t*)(smem + aB + mt * 128);
    if (t + 3 < nt32) STAGE2(A0, A1, t + 3, 0);
    __builtin_amdgcn_s_barrier();
    asm volatile("s_waitcnt lgkmcnt(0)" ::: "memory");
    __builtin_amdgcn_sched_barrier(0);
    __builtin_amdgcn_s_setprio(1);
#pragma unroll
    for (int mt = 0; mt < 4; mt++)
#pragma unroll
      for (int nt = 0; nt < 4; nt++)
        acc[mt][nt] = mfma16x16x32(af[mt], bfr[nt], acc[mt][nt]);
    __builtin_amdgcn_s_setprio(0);
    __builtin_amdgcn_s_barrier();

    // ---- phase 1 (row-half 1) ----
#pragma unroll
    for (int mt = 0; mt < 4; mt++) af[mt] = *(const frag_t*)(smem + aB + 512 + mt * 128);
    if (t + 3 < nt32) STAGE2(B0, B1, t + 3, 2);
    __builtin_amdgcn_s_barrier();
    asm volatile("s_waitcnt lgkmcnt(0)" ::: "memory");
    __builtin_amdgcn_sched_barrier(0);
    __builtin_amdgcn_s_setprio(1);
#pragma unroll
    for (int mt = 0; mt < 4; mt++)
#pragma unroll
      for (int nt = 0; nt < 4; nt++)
        acc[4 + mt][nt] = mfma16x16x32(af[mt], bfr[nt], acc[4 + mt][nt]);
    __builtin_amdgcn_s_setprio(0);

    // Counted boundary wait: tile t+1 must be resident; keep t+2,t+3 in flight.
    if (t + 4 <= nt32)      { asm volatile("s_waitcnt vmcnt(8)" ::: "memory"); }
    else if (t + 3 <= nt32) { asm volatile("s_waitcnt vmcnt(4)" ::: "memory"); }
    else if (t + 2 <= nt32) { asm volatile("s_waitcnt vmcnt(0)" ::: "memory"); }
    __builtin_amdgcn_s_barrier();
  }
#undef STAGE2
}

// Packed bf16 epilogue for the 256^2 tile: repack through LDS (128 KB image),
// then 2 x 32768-u16 contiguous chunk groups to dst0/dst1 (row-blocks 2bx,2bx+1).
__device__ __forceinline__ void epi_pack256(u16* smem, u16* __restrict__ dst0,
                                            u16* __restrict__ dst1, f32x4 acc[8][4])
{
  const int tid   = threadIdx.x;
  const int lane  = tid & 63;
  const int wave  = tid >> 6;
  const int quad  = lane >> 4;
  const int l16   = lane & 15;
  const int waveM = wave >> 2;
  const int waveN = wave & 3;

  __syncthreads();
#pragma unroll
  for (int m8 = 0; m8 < 8; m8++)
#pragma unroll
    for (int nt = 0; nt < 4; nt++) {
      const int base = waveM * 32768 + waveN * 8192 + (nt * 2 + (l16 >> 3)) * 1024
                     + (l16 & 7);
#pragma unroll
      for (int i = 0; i < 4; i++) {
        const int r = m8 * 16 + quad * 4 + i;  // local row within 128-block
        smem[base + r * 8] = f2bf(acc[m8][nt][i]);
      }
    }
  __syncthreads();
#pragma unroll
  for (int k = 0; k < 8; k++) {
    const int idx = k * 4096 + tid * 8;
    *(uint4*)(dst0 + idx) = *(const uint4*)(smem + idx);
    *(uint4*)(dst1 + idx) = *(const uint4*)(smem + 32768 + idx);
  }
}

// Exp + packed + row-sum epilogue for the 256^2 S-GEMM.
__device__ __forceinline__ void epi_exp256(u16* smem, u16* __restrict__ dst0,
                                           u16* __restrict__ dst1,
                                           float* __restrict__ lpart,
                                           f32x4 acc[8][4], float qscale)
{
  const int tid   = threadIdx.x;
  const int lane  = tid & 63;
  const int wave  = tid >> 6;
  const int quad  = lane >> 4;
  const int l16   = lane & 15;
  const int waveM = wave >> 2;
  const int waveN = wave & 3;
  float* lrow = (float*)(smem + 65536);  // [256][4] floats (4 KB)

  __syncthreads();
  float s[8][4];
#pragma unroll
  for (int m8 = 0; m8 < 8; m8++)
#pragma unroll
    for (int i = 0; i < 4; i++) s[m8][i] = 0.f;

#pragma unroll
  for (int m8 = 0; m8 < 8; m8++)
#pragma unroll
    for (int nt = 0; nt < 4; nt++) {
      const int base = waveM * 32768 + waveN * 8192 + (nt * 2 + (l16 >> 3)) * 1024
                     + (l16 & 7);
#pragma unroll
      for (int i = 0; i < 4; i++) {
        const int r = m8 * 16 + quad * 4 + i;
        float ev = __expf(acc[m8][nt][i] * qscale);
        smem[base + r * 8] = f2bf(ev);
        s[m8][i] += ev;
      }
    }
#pragma unroll
  for (int m8 = 0; m8 < 8; m8++)
#pragma unroll
    for (int i = 0; i < 4; i++) {
      float v = s[m8][i];
      v += __shfl_xor(v, 1, 16);
      v += __shfl_xor(v, 2, 16);
      v += __shfl_xor(v, 4, 16);
      v += __shfl_xor(v, 8, 16);
      if (l16 == 0)
        lrow[(waveM * 128 + m8 * 16 + quad * 4 + i) * 4 + waveN] = v;
    }
  __syncthreads();
#pragma unroll
  for (int k = 0; k < 8; k++) {
    const int idx = k * 4096 + tid * 8;
    *(uint4*)(dst0 + idx) = *(const uint4*)(smem + idx);
    *(uint4*)(dst1 + idx) = *(const uint4*)(smem + 32768 + idx);
  }
  if (tid < 256)
    lpart[tid] = lrow[tid * 4] + lrow[tid * 4 + 1] + lrow[tid * 4 + 2] + lrow[tid * 4 + 3];
}

// =====================================================================
// Merged Q/K/V^T projection, 256^2 tiles: grid 288.
//  x < 192 : QK-proj, bx = x&31 (row-tile), by = x>>5 (0..2 Q, 3..5 K)
//  x >= 192: V^T-proj, i = x-192, bx = i>>5 (u-tile 0..2), by = i&31 (seq-tile)
// =====================================================================
__global__ __launch_bounds__(512, 2)
void gemm_proj256(const u16* __restrict__ xbp, const u16* __restrict__ wtp,
                  u16* __restrict__ Qp, u16* __restrict__ Kp, u16* __restrict__ Vtp)
{
  __shared__ alignas(16) u16 smem[65536];
  f32x4 acc[8][4];
  const int x = blockIdx.x;
  const u16 *A0, *A1, *B0, *B1;
  u16 *d0, *d1;
  if (x < 192) {
    const int bx = x & 31, by = x >> 5;
    A0 = xbp + (long)(2 * bx) * 98304;  A1 = A0 + 98304;
    B0 = wtp + (long)(2 * by) * 98304;  B1 = B0 + 98304;
    d0 = (by < 3) ? Qp + (long)(2 * bx) * 98304 + (long)(4 * by) * GR
                  : Kp + (long)(2 * bx) * 98304 + (long)(4 * (by - 3)) * GR;
    d1 = d0 + 98304;
  } else {
    const int i = x - 192;
    const int bx = i >> 5, by = i & 31;
    A0 = wtp + (long)(12 + 2 * bx) * 98304;  A1 = A0 + 98304;
    B0 = xbp + (long)(2 * by) * 98304;       B1 = B0 + 98304;
    d0 = Vtp + (long)(2 * bx) * 1048576 + (long)(4 * by) * GR;
    d1 = d0 + 1048576;
  }
  gemm256_loop(smem, A0, A1, B0, B1, 24, acc);
  epi_pack256(smem, d0, d1, acc);
}

// =====================================================================
// S-GEMM + fused exp/row-sum, 256^2 tiles: grid (8,8,gb) == 256 blocks/batch-group.
// =====================================================================
__global__ __launch_bounds__(512, 2)
void gemm_s_exp256(const u16* __restrict__ Qp, const u16* __restrict__ Kp,
                   u16* __restrict__ Pp, float* __restrict__ l_part, float qscale)
{
  __shared__ alignas(16) u16 smem[67584];  // 128 KB image + 4 KB lrow
  f32x4 acc[8][4];
  const int bx = blockIdx.x, by = blockIdx.y, z = blockIdx.z;
  const u16* A0 = Qp + (long)(z * 16 + 2 * bx) * 98304;
  const u16* B0 = Kp + (long)(z * 16 + 2 * by) * 98304;
  gemm256_loop(smem, A0, A0 + 98304, B0, B0 + 98304, 24, acc);
  u16* d0 = Pp + (long)z * 4194304 + (long)(2 * bx) * 262144 + (long)(4 * by) * GR;
  epi_exp256(smem, d0, d0 + 262144,
             l_part + ((long)z * 8 + by) * 2048 + bx * 256, acc, qscale);
}

// l_inv[z][q] = 1 / sum_j l_part[z][j][q]   (8 col-tile partials now)
__global__ __launch_bounds__(256)
void sum_l_inv(const float* __restrict__ lpart, float* __restrict__ linv, int n)
{
  int i = blockIdx.x * 256 + threadIdx.x;
  if (i >= n) return;
  const int z = i >> 11;
  const float* p = lpart + (long)z * 16384 + (i & 2047);
  float s = 0.f;
#pragma unroll
  for (int j = 0; j < 8; j++) s += p[j * 2048];
  linv[i] = 1.0f / s;
}

// =====================================================================
// One-shot PV (K=2048, NIT=32), grid (16,6,gb) — unchanged this round.
// =====================================================================
__global__ __launch_bounds__(256)
void gemm_pv(const u16* __restrict__ Pp, const u16* __restrict__ Vtp_off,
             const float* __restrict__ linv, float* __restrict__ out)
{
  __shared__ alignas(16) u16 smem[16384];
  f32x4 acc[4][4];
  const long SU = 2048L * 768;
  const int bx = blockIdx.x, by = blockIdx.y, z = blockIdx.z;
  gemm_loop4(smem,
             Pp + (long)z * 4194304 + (long)bx * 262144,
             Vtp_off + (long)by * 1048576 + (long)(z * 32) * GR,
             32, acc);

  __syncthreads();
  float* lsl = (float*)smem;
  const int tid = threadIdx.x;
  if (tid < 128) lsl[tid] = linv[(long)z * 2048 + bx * 128 + tid];
  __syncthreads();

  const int lane = tid & 63;
  const int wave = tid >> 6;
  const int quad = lane >> 4;
  const int l16  = lane & 15;
  const int wm   = (wave & 1) * 64;
  const int wn   = (wave >> 1) * 64;
  float* C = out + (long)z * SU;
#pragma unroll
  for (int mt = 0; mt < 4; mt++)
#pragma unroll
    for (int nt = 0; nt < 4; nt++) {
      const int r0 = bx * 128 + wm + mt * 16 + quad * 4;
      const int lr = wm + mt * 16 + quad * 4;
      const int cc = by * 128 + wn + nt * 16 + l16;
#pragma unroll
      for (int i = 0; i < 4; i++)
        C[(long)(r0 + i) * 768 + cc] = acc[mt][nt][i] * lsl[lr + i];
    }
}

// =====================================================================
// x [8192 x 768] fp32 -> packed bf16 [64 blocks][12 its]. 8 elems/thread.
// =====================================================================
__global__ __launch_bounds__(256)
void convert_pack(const float* __restrict__ x, u16* __restrict__ xbp)
{
  const int tg = blockIdx.x * 256 + threadIdx.x;
  const int m = tg / 96;
  const int g = tg - m * 96;
  const float4* px = (const float4*)(x + (long)m * 768 + g * 8);
  float4 a = px[0], b = px[1];
  uint4 u;
  u.x = (u32)f2bf(a.x) | ((u32)f2bf(a.y) << 16);
  u.y = (u32)f2bf(a.z) | ((u32)f2bf(a.w) << 16);
  u.z = (u32)f2bf(b.x) | ((u32)f2bf(b.y) << 16);
  u.w = (u32)f2bf(b.z) | ((u32)f2bf(b.w) << 16);
  const long addr = (long)(m >> 7) * 98304 + (g >> 3) * GR + (g & 7) * 1024 + (m & 127) * 8;
  *(uint4*)(xbp + addr) = u;
}

// =====================================================================
// W [768x768] fp32 -> W^T packed bf16 into wtp blocks z*6 .. z*6+5.
// =====================================================================
__global__ __launch_bounds__(256)
void transpose_pack_w(const float* __restrict__ W0, const float* __restrict__ W1,
                      const float* __restrict__ W2, u16* __restrict__ wtp)
{
  const float* W = blockIdx.z == 0 ? W0 : (blockIdx.z == 1 ? W1 : W2);
  __shared__ u16 tile[32][33];
  const int bx = blockIdx.x * 32;
  const int by = blockIdx.y * 32;
  const int tx = threadIdx.x, ty = threadIdx.y;
#pragma unroll
  for (int i = 0; i < 32; i += 8)
    tile[ty + i][tx] = f2bf(W[(long)(by + ty + i) * 768 + bx + tx]);
  __syncthreads();
  const int t = ty * 32 + tx;
  if (t < 128) {
    const int ul = t >> 2, dg = t & 3;
    const int u = bx + ul, d0 = by + dg * 8;
    uint4 o;
    u32 w_[4];
#pragma unroll
    for (int i = 0; i < 4; i++)
      w_[i] = (u32)tile[dg * 8 + 2 * i][ul] | ((u32)tile[dg * 8 + 2 * i + 1][ul] << 16);
    o.x = w_[0]; o.y = w_[1]; o.z = w_[2]; o.w = w_[3];
    const long addr = (long)(blockIdx.z * 6 + (u >> 7)) * 98304
                    + (d0 >> 6) * GR + ((d0 >> 3) & 7) * 1024 + (u & 127) * 8;
    *(uint4*)(wtp + addr) = o;
  }
}

// =====================================================================
extern "C" void kernel_launch(void* const* d_in, const int* in_sizes, int n_in,
                              void* d_out, int out_size, void* d_ws, size_t ws_size,
                              hipStream_t stream) {
  (void)in_sizes; (void)n_in; (void)out_size;
  const float* x  = (const float*)d_in[0];
  const float* Wq = (const float*)d_in[1];
  const float* Wk = (const float*)d_in[2];
  const float* Wv = (const float*)d_in[3];
  float* out = (float*)d_out;

  const long SU = 2048L * 768;

  u16* ws  = (u16*)d_ws;
  u16* xbp = ws;                  // packed x      [64][12]  6,291,456 u16
  u16* wtp = xbp + 6291456;       // packed W^T    [18][12]  1,769,472
  u16* Qp  = wtp + 1769472;       // packed Q      [64][12]  6,291,456
  u16* Kp  = Qp + 6291456;        // packed K      [64][12]  6,291,456
  u16* Vtp = Kp + 6291456;        // packed V^T    [6][128]  6,291,456
  char* rest = (char*)(Vtp + 6291456);
  size_t fixed = (size_t)(rest - (char*)d_ws);
  size_t per_b = (size_t)4194304 * 2 + 32768 * 4 + 2048 * 4;

  int g = 1;
  if (ws_size >= fixed + 4 * per_b) g = 4;
  else if (ws_size >= fixed + 2 * per_b) g = 2;

  u16*   Pp     = (u16*)rest;
  float* l_part = (float*)(Pp + (size_t)g * 4194304);
  float* l_inv  = l_part + (size_t)g * 32768;

  const float qscale = 0.03608439182435161f;  // 1/sqrt(768)

  convert_pack<<<dim3(3072), dim3(256), 0, stream>>>(x, xbp);
  transpose_pack_w<<<dim3(24, 24, 3), dim3(32, 8), 0, stream>>>(Wq, Wk, Wv, wtp);

  gemm_proj256<<<dim3(288), dim3(512), 0, stream>>>(xbp, wtp, Qp, Kp, Vtp);

  for (int b0 = 0; b0 < 4; b0 += g) {
    int gb = 4 - b0 < g ? 4 - b0 : g;
    gemm_s_exp256<<<dim3(8, 8, gb), dim3(512), 0, stream>>>(
        Qp + (long)b0 * 16 * 98304, Kp + (long)b0 * 16 * 98304, Pp, l_part, qscale);
    sum_l_inv<<<dim3(gb * 8), dim3(256), 0, stream>>>(l_part, l_inv, gb * 2048);
    gemm_pv<<<dim3(16, 6, gb), dim3(256), 0, stream>>>(
        Pp, Vtp + (long)b0 * 32 * GR, l_inv, out + (long)b0 * SU);
  }
}

// Round 3
// 201.980 us; speedup vs baseline: 1.0454x; 1.0454x over previous
//
#include <hip/hip_runtime.h>
#include <stdint.h>

// Self-attention: x[4,2048,768] fp32, W_q/W_k/W_v [768,768] fp32 -> out[4,2048,768] fp32.
//
// v8 (resubmission — round-2 bench died in infra; kernel audited OOB/deadlock/race-clean):
//  - 256x128-tile 8-wave BK=32 triple-buffered core (72 KiB LDS -> 2 blocks/CU
//    capacity), counted vmcnt(3) boundary waits, setprio around 16-MFMA clusters.
//  - s_exp: grid (8,16,g) -> 256 blocks per batch-pair (full fill at g=2).
//  - proj: 576 tiles of 256x128 (32x12 QK + 3x64 V^T), 2/CU packing vs 288's 2 rounds.
//  - g=4 attempt: P overlaps post-proj-dead xbp+wtp (peak 71.9 MB); ladder g=4/2/1.
//  - PV kept as 128^2 4-wave core (single 384-block launch at g=4).
//
// Packed layout: operand = [row-block r/128][it = k/64][16 KB chunk]; chunk =
// [p = k-octet 0..8][r 0..128][8 u16]. A 32-k piece = half-chunk = 4096 u16;
// piece offset for 32-k tile t = t*4096.

typedef unsigned short u16;
typedef unsigned int u32;

typedef __attribute__((ext_vector_type(4))) float f32x4;
typedef __attribute__((ext_vector_type(8))) __bf16 bf16x8;
typedef __attribute__((ext_vector_type(8))) short s16x8;
typedef __attribute__((ext_vector_type(8))) unsigned short us16x8;

template <class T> T&& declv();
template <typename T, typename V = void>
struct mfma_ok { static constexpr bool value = false; };
template <typename T>
struct mfma_ok<T, decltype((void)__builtin_amdgcn_mfma_f32_16x16x32_bf16(
                     declv<T>(), declv<T>(), declv<f32x4>(), 0, 0, 0))> {
  static constexpr bool value = true;
};
template <bool BF, bool S16> struct pick_frag { typedef us16x8 type; };
template <bool S16> struct pick_frag<true, S16> { typedef bf16x8 type; };
template <> struct pick_frag<false, true> { typedef s16x8 type; };
typedef typename pick_frag<mfma_ok<bf16x8>::value, mfma_ok<s16x8>::value>::type frag_t;

__device__ inline f32x4 mfma16x16x32(frag_t a, frag_t b, f32x4 c) {
  return __builtin_amdgcn_mfma_f32_16x16x32_bf16(a, b, c, 0, 0, 0);
}

#define AS3(p) ((__attribute__((address_space(3))) void*)(p))
#define AS1c(p) ((__attribute__((address_space(1))) void*)(const void*)(p))

__device__ inline u16 f2bf(float f) {
  union { float f; u32 u; } v; v.f = f;
  u32 r = v.u + 0x7fffu + ((v.u >> 16) & 1u);  // RNE
  return (u16)(r >> 16);
}

#define GR 8192        // u16 per it-chunk (16 KB)
#define BOFF4 8192     // u16 offset of B half of LDS (128^2 loop)

// =====================================================================
// 128x128 / 4-wave loop — kept for gemm_pv only.
// =====================================================================
__device__ inline void gemm_loop4(u16* smem, const u16* __restrict__ Ap,
                                  const u16* __restrict__ Bp, int nit,
                                  f32x4 acc[4][4])
{
  const int tid  = threadIdx.x;
  const int lane = tid & 63;
  const int wave = tid >> 6;
  const int quad = lane >> 4;
  const int l16  = lane & 15;
  const int wm   = (wave & 1) * 64;
  const int wn   = (wave >> 1) * 64;
  const int so   = wave * 2048;
  const int lo   = lane << 3;

#pragma unroll
  for (int i = 0; i < 4; i++)
#pragma unroll
    for (int j = 0; j < 4; j++) acc[i][j] = f32x4{0.f, 0.f, 0.f, 0.f};

  for (int it = 0; it < nit; ++it) {
    const long o = (long)it * GR;
    __syncthreads();
#pragma unroll
    for (int j = 0; j < 4; j++) {
      __builtin_amdgcn_global_load_lds(AS1c(Ap + o + so + j * 512 + lo),
                                       AS3(smem + so + j * 512), 16, 0, 0);
      __builtin_amdgcn_global_load_lds(AS1c(Bp + o + so + j * 512 + lo),
                                       AS3(smem + BOFF4 + so + j * 512), 16, 0, 0);
    }
    __syncthreads();

#pragma unroll
    for (int s = 0; s < 2; s++) {
      frag_t af[4], bf_[4];
#pragma unroll
      for (int mt = 0; mt < 4; mt++)
        af[mt] = *(const frag_t*)(&smem[(s * 4 + quad) * 1024 + (wm + mt * 16 + l16) * 8]);
#pragma unroll
      for (int nt = 0; nt < 4; nt++)
        bf_[nt] = *(const frag_t*)(&smem[BOFF4 + (s * 4 + quad) * 1024 + (wn + nt * 16 + l16) * 8]);
#pragma unroll
      for (int mt = 0; mt < 4; mt++)
#pragma unroll
        for (int nt = 0; nt < 4; nt++)
          acc[mt][nt] = mfma16x16x32(af[mt], bf_[nt], acc[mt][nt]);
    }
  }
}

// =====================================================================
// 256x128 / 8-wave / BK=32 / triple-buffered core (72 KiB LDS).
// Buffer b at b*12288 u16: [A0 4096][A1 4096][B 4096]; piece = 32-k half-chunk.
// Waves 4M x 2N; per-wave output 64x64 (4x4 16x16x32 frags).
// Per tile: {8 ds_read_b128, stage tile t+2 (3 gloads), barrier, lgkmcnt(0),
//   sched_barrier, setprio(1), 16 MFMA, setprio(0), boundary vmcnt(3), barrier}.
// Race-free: stage of t+2 targets buf (t+2)%3 == (t-1)%3, fully read before the
// end-of-(t-1) barrier (every wave drains lgkmcnt before its MFMA).
// =====================================================================
__device__ __forceinline__ void gemm128c_loop(u16* smem,
    const u16* __restrict__ A0, const u16* __restrict__ A1,
    const u16* __restrict__ B0, int nt32, f32x4 acc[4][4])
{
  const int tid   = threadIdx.x;
  const int lane  = tid & 63;
  const int wave  = tid >> 6;      // 0..7
  const int quad  = lane >> 4;
  const int l16   = lane & 15;
  const int waveM = wave >> 1;     // 0..3 (64-row strip)
  const int waveN = wave & 1;      // 0..1 (64-col strip)
  const int wch   = wave * 512;    // wave chunk within a 4096-u16 piece
  const int go    = tid * 8;       // per-lane global offset (u16)

#pragma unroll
  for (int i = 0; i < 4; i++)
#pragma unroll
    for (int j = 0; j < 4; j++) acc[i][j] = f32x4{0.f, 0.f, 0.f, 0.f};

#define STG3(T, BUF) do {                                                      \
    const long _p = (long)(T) * 4096;                                          \
    const int _b = (BUF) * 12288 + wch;                                        \
    __builtin_amdgcn_global_load_lds(AS1c(A0 + _p + go), AS3(smem + _b),       \
                                     16, 0, 0);                                \
    __builtin_amdgcn_global_load_lds(AS1c(A1 + _p + go), AS3(smem + _b + 4096),\
                                     16, 0, 0);                                \
    __builtin_amdgcn_global_load_lds(AS1c(B0 + _p + go), AS3(smem + _b + 8192),\
                                     16, 0, 0);                                \
  } while (0)

  // Prologue: stage tiles 0,1 (6 loads/thread); wait tile 0 (3 newest pending).
  STG3(0, 0);
  STG3(1, 1);
  asm volatile("s_waitcnt vmcnt(3)" ::: "memory");
  __builtin_amdgcn_s_barrier();

  const int ablk = (waveM >> 1) * 4096;          // which A piece (rows 0..127 / 128..255)
  const int arow = ((waveM & 1) * 64 + l16) * 8; // row base within piece
  const int brow = (waveN * 64 + l16) * 8;

  int bc = 0;  // t % 3
  for (int t = 0; t < nt32; ++t) {
    const int bb = bc * 12288;
    frag_t af[4], bfr[4];
#pragma unroll
    for (int mt = 0; mt < 4; mt++)
      af[mt] = *(const frag_t*)(smem + bb + ablk + quad * 1024 + arow + mt * 128);
#pragma unroll
    for (int nt = 0; nt < 4; nt++)
      bfr[nt] = *(const frag_t*)(smem + bb + 8192 + quad * 1024 + brow + nt * 128);

    if (t + 2 < nt32) {
      const int sc = bc == 0 ? 2 : bc - 1;  // (t+2) % 3
      STG3(t + 2, sc);
    }
    __builtin_amdgcn_s_barrier();
    asm volatile("s_waitcnt lgkmcnt(0)" ::: "memory");
    __builtin_amdgcn_sched_barrier(0);
    __builtin_amdgcn_s_setprio(1);
#pragma unroll
    for (int mt = 0; mt < 4; mt++)
#pragma unroll
      for (int nt = 0; nt < 4; nt++)
        acc[mt][nt] = mfma16x16x32(af[mt], bfr[nt], acc[mt][nt]);
    __builtin_amdgcn_s_setprio(0);

    // Boundary: ensure tile t+1 resident; keep t+2 in flight. Never 0 mid-loop.
    if (t + 3 <= nt32)      { asm volatile("s_waitcnt vmcnt(3)" ::: "memory"); }
    else if (t + 2 <= nt32) { asm volatile("s_waitcnt vmcnt(0)" ::: "memory"); }
    __builtin_amdgcn_s_barrier();
    bc = bc == 2 ? 0 : bc + 1;
  }
#undef STG3
}

// Packed bf16 epilogue for a 256x128 tile: 64 KB image -> dst0 (row-block 0,
// 2 it-chunks = 16384 u16) + dst1 (row-block 1).
__device__ __forceinline__ void epi_pack_rc(u16* smem, u16* __restrict__ dst0,
                                            u16* __restrict__ dst1, f32x4 acc[4][4])
{
  const int tid   = threadIdx.x;
  const int lane  = tid & 63;
  const int wave  = tid >> 6;
  const int quad  = lane >> 4;
  const int l16   = lane & 15;
  const int waveM = wave >> 1;
  const int waveN = wave & 1;

  __syncthreads();
  const int base = (waveM >> 1) * 16384 + waveN * 8192 + (l16 >> 3) * 1024 + (l16 & 7);
  const int rr0  = (waveM & 1) * 64 + quad * 4;
#pragma unroll
  for (int mt = 0; mt < 4; mt++)
#pragma unroll
    for (int nt = 0; nt < 4; nt++) {
#pragma unroll
      for (int i = 0; i < 4; i++)
        smem[base + nt * 2048 + (rr0 + mt * 16 + i) * 8] = f2bf(acc[mt][nt][i]);
    }
  __syncthreads();
#pragma unroll
  for (int k = 0; k < 4; k++) {
    const int idx = k * 4096 + tid * 8;
    *(uint4*)(dst0 + idx) = *(const uint4*)(smem + idx);
    *(uint4*)(dst1 + idx) = *(const uint4*)(smem + 16384 + idx);
  }
}

// Exp + packed + row-sum epilogue for a 256x128 S-tile.
__device__ __forceinline__ void epi_exp_rc(u16* smem, u16* __restrict__ dst0,
                                           u16* __restrict__ dst1,
                                           float* __restrict__ lpart,
                                           f32x4 acc[4][4], float qscale)
{
  const int tid   = threadIdx.x;
  const int lane  = tid & 63;
  const int wave  = tid >> 6;
  const int quad  = lane >> 4;
  const int l16   = lane & 15;
  const int waveM = wave >> 1;
  const int waveN = wave & 1;
  float* lrow = (float*)(smem + 32768);  // [256][2] floats (2 KB)

  __syncthreads();
  const int base = (waveM >> 1) * 16384 + waveN * 8192 + (l16 >> 3) * 1024 + (l16 & 7);
  const int rr0  = (waveM & 1) * 64 + quad * 4;
  float s[4][4];
#pragma unroll
  for (int mt = 0; mt < 4; mt++)
#pragma unroll
    for (int i = 0; i < 4; i++) s[mt][i] = 0.f;

#pragma unroll
  for (int mt = 0; mt < 4; mt++)
#pragma unroll
    for (int nt = 0; nt < 4; nt++) {
#pragma unroll
      for (int i = 0; i < 4; i++) {
        float ev = __expf(acc[mt][nt][i] * qscale);
        smem[base + nt * 2048 + (rr0 + mt * 16 + i) * 8] = f2bf(ev);
        s[mt][i] += ev;
      }
    }
#pragma unroll
  for (int mt = 0; mt < 4; mt++)
#pragma unroll
    for (int i = 0; i < 4; i++) {
      float v = s[mt][i];
      v += __shfl_xor(v, 1, 16);
      v += __shfl_xor(v, 2, 16);
      v += __shfl_xor(v, 4, 16);
      v += __shfl_xor(v, 8, 16);
      if (l16 == 0)
        lrow[(waveM * 64 + mt * 16 + quad * 4 + i) * 2 + waveN] = v;
    }
  __syncthreads();
#pragma unroll
  for (int k = 0; k < 4; k++) {
    const int idx = k * 4096 + tid * 8;
    *(uint4*)(dst0 + idx) = *(const uint4*)(smem + idx);
    *(uint4*)(dst1 + idx) = *(const uint4*)(smem + 16384 + idx);
  }
  if (tid < 256) lpart[tid] = lrow[tid * 2] + lrow[tid * 2 + 1];
}

// =====================================================================
// Merged Q/K/V^T projection, 256x128 tiles: grid 576.
//  x < 384 : QK-proj, bx = x&31 (256-row tile), by = x>>5 (128-col strip: 0..5 Q, 6..11 K)
//  x >= 384: V^T-proj, i = x-384, bxv = i>>6 (256-u tile 0..2), byv = i&63 (128-seq strip)
// =====================================================================
__global__ __launch_bounds__(512, 2)
void gemm_proj(const u16* __restrict__ xbp, const u16* __restrict__ wtp,
               u16* __restrict__ Qp, u16* __restrict__ Kp, u16* __restrict__ Vtp)
{
  __shared__ alignas(16) u16 smem[36864];
  f32x4 acc[4][4];
  const int x = blockIdx.x;
  const u16 *A0, *A1, *B0;
  u16 *d0, *d1;
  if (x < 384) {
    const int bx = x & 31, by = x >> 5;
    A0 = xbp + (long)(2 * bx) * 98304;  A1 = A0 + 98304;
    B0 = wtp + (long)by * 98304;
    d0 = (by < 6) ? Qp + (long)(2 * bx) * 98304 + (long)(2 * by) * GR
                  : Kp + (long)(2 * bx) * 98304 + (long)(2 * (by - 6)) * GR;
    d1 = d0 + 98304;
  } else {
    const int i = x - 384;
    const int bxv = i >> 6, byv = i & 63;
    A0 = wtp + (long)(12 + 2 * bxv) * 98304;  A1 = A0 + 98304;
    B0 = xbp + (long)byv * 98304;
    d0 = Vtp + (long)(2 * bxv) * 1048576 + (long)(2 * byv) * GR;
    d1 = d0 + 1048576;
  }
  gemm128c_loop(smem, A0, A1, B0, 24, acc);
  epi_pack_rc(smem, d0, d1, acc);
}

// =====================================================================
// S-GEMM + fused exp/row-sum, 256x128 tiles: grid (8,16,gb) == 256 blocks/batch.
// =====================================================================
__global__ __launch_bounds__(512, 2)
void gemm_s_exp(const u16* __restrict__ Qp, const u16* __restrict__ Kp,
                u16* __restrict__ Pp, float* __restrict__ l_part, float qscale)
{
  __shared__ alignas(16) u16 smem[36864];
  f32x4 acc[4][4];
  const int bx = blockIdx.x, by = blockIdx.y, z = blockIdx.z;
  const u16* A0 = Qp + (long)(z * 16 + 2 * bx) * 98304;
  const u16* B0 = Kp + (long)(z * 16 + by) * 98304;
  gemm128c_loop(smem, A0, A0 + 98304, B0, 24, acc);
  u16* d0 = Pp + (long)z * 4194304 + (long)(2 * bx) * 262144 + (long)(2 * by) * GR;
  epi_exp_rc(smem, d0, d0 + 262144,
             l_part + ((long)z * 16 + by) * 2048 + bx * 256, acc, qscale);
}

// l_inv[z][q] = 1 / sum_j l_part[z][j][q]  (16 col-strip partials)
__global__ __launch_bounds__(256)
void sum_l_inv(const float* __restrict__ lpart, float* __restrict__ linv, int n)
{
  int i = blockIdx.x * 256 + threadIdx.x;
  if (i >= n) return;
  const int z = i >> 11;
  const float* p = lpart + (long)z * 32768 + (i & 2047);
  float s = 0.f;
#pragma unroll
  for (int j = 0; j < 16; j++) s += p[j * 2048];
  linv[i] = 1.0f / s;
}

// =====================================================================
// One-shot PV (K=2048, NIT=32), grid (16,6,gb); z = batch (group-local).
// =====================================================================
__global__ __launch_bounds__(256)
void gemm_pv(const u16* __restrict__ Pp, const u16* __restrict__ Vtp_off,
             const float* __restrict__ linv, float* __restrict__ out)
{
  __shared__ alignas(16) u16 smem[16384];
  f32x4 acc[4][4];
  const long SU = 2048L * 768;
  const int bx = blockIdx.x, by = blockIdx.y, z = blockIdx.z;
  gemm_loop4(smem,
             Pp + (long)z * 4194304 + (long)bx * 262144,
             Vtp_off + (long)by * 1048576 + (long)(z * 32) * GR,
             32, acc);

  __syncthreads();
  float* lsl = (float*)smem;
  const int tid = threadIdx.x;
  if (tid < 128) lsl[tid] = linv[(long)z * 2048 + bx * 128 + tid];
  __syncthreads();

  const int lane = tid & 63;
  const int wave = tid >> 6;
  const int quad = lane >> 4;
  const int l16  = lane & 15;
  const int wm   = (wave & 1) * 64;
  const int wn   = (wave >> 1) * 64;
  float* C = out + (long)z * SU;
#pragma unroll
  for (int mt = 0; mt < 4; mt++)
#pragma unroll
    for (int nt = 0; nt < 4; nt++) {
      const int r0 = bx * 128 + wm + mt * 16 + quad * 4;
      const int lr = wm + mt * 16 + quad * 4;
      const int cc = by * 128 + wn + nt * 16 + l16;
#pragma unroll
      for (int i = 0; i < 4; i++)
        C[(long)(r0 + i) * 768 + cc] = acc[mt][nt][i] * lsl[lr + i];
    }
}

// =====================================================================
// x [8192 x 768] fp32 -> packed bf16 [64 blocks][12 its]. 8 elems/thread.
// =====================================================================
__global__ __launch_bounds__(256)
void convert_pack(const float* __restrict__ x, u16* __restrict__ xbp)
{
  const int tg = blockIdx.x * 256 + threadIdx.x;
  const int m = tg / 96;
  const int g = tg - m * 96;
  const float4* px = (const float4*)(x + (long)m * 768 + g * 8);
  float4 a = px[0], b = px[1];
  uint4 u;
  u.x = (u32)f2bf(a.x) | ((u32)f2bf(a.y) << 16);
  u.y = (u32)f2bf(a.z) | ((u32)f2bf(a.w) << 16);
  u.z = (u32)f2bf(b.x) | ((u32)f2bf(b.y) << 16);
  u.w = (u32)f2bf(b.z) | ((u32)f2bf(b.w) << 16);
  const long addr = (long)(m >> 7) * 98304 + (g >> 3) * GR + (g & 7) * 1024 + (m & 127) * 8;
  *(uint4*)(xbp + addr) = u;
}

// =====================================================================
// W [768x768] fp32 -> W^T packed bf16 into wtp blocks z*6 .. z*6+5.
// =====================================================================
__global__ __launch_bounds__(256)
void transpose_pack_w(const float* __restrict__ W0, const float* __restrict__ W1,
                      const float* __restrict__ W2, u16* __restrict__ wtp)
{
  const float* W = blockIdx.z == 0 ? W0 : (blockIdx.z == 1 ? W1 : W2);
  __shared__ u16 tile[32][33];
  const int bx = blockIdx.x * 32;
  const int by = blockIdx.y * 32;
  const int tx = threadIdx.x, ty = threadIdx.y;
#pragma unroll
  for (int i = 0; i < 32; i += 8)
    tile[ty + i][tx] = f2bf(W[(long)(by + ty + i) * 768 + bx + tx]);
  __syncthreads();
  const int t = ty * 32 + tx;
  if (t < 128) {
    const int ul = t >> 2, dg = t & 3;
    const int u = bx + ul, d0 = by + dg * 8;
    uint4 o;
    u32 w_[4];
#pragma unroll
    for (int i = 0; i < 4; i++)
      w_[i] = (u32)tile[dg * 8 + 2 * i][ul] | ((u32)tile[dg * 8 + 2 * i + 1][ul] << 16);
    o.x = w_[0]; o.y = w_[1]; o.z = w_[2]; o.w = w_[3];
    const long addr = (long)(blockIdx.z * 6 + (u >> 7)) * 98304
                    + (d0 >> 6) * GR + ((d0 >> 3) & 7) * 1024 + (u & 127) * 8;
    *(uint4*)(wtp + addr) = o;
  }
}

// =====================================================================
extern "C" void kernel_launch(void* const* d_in, const int* in_sizes, int n_in,
                              void* d_out, int out_size, void* d_ws, size_t ws_size,
                              hipStream_t stream) {
  (void)in_sizes; (void)n_in; (void)out_size;
  const float* x  = (const float*)d_in[0];
  const float* Wq = (const float*)d_in[1];
  const float* Wk = (const float*)d_in[2];
  const float* Wv = (const float*)d_in[3];
  float* out = (float*)d_out;

  const long SU = 2048L * 768;

  // Layout (bytes from ws base):
  //   [Qp 12.58M][Kp 12.58M][Vtp 12.58M][lpart 512K][linv 32K]   front = 38,305,792
  //   [xbp 12.58M][wtp 3.54M]                                    end   = 54,427,648
  //   P (g x 8.39M) overlaps xbp base (xbp/wtp dead after proj): end(g=4) = 71,860,224
  u16* W = (u16*)d_ws;
  u16* Qp  = W;
  u16* Kp  = Qp + 6291456;
  u16* Vtp = Kp + 6291456;
  float* l_part = (float*)(Vtp + 6291456);
  float* l_inv  = l_part + 131072;
  u16* xbp = (u16*)((char*)d_ws + 38305792);
  u16* wtp = xbp + 6291456;
  u16* Pp  = xbp;  // overlaps xbp+wtp (dead after proj)

  const size_t need4 = 38305792u + 4u * 8388608u;   // 71,860,224
  const size_t need2 = 38305792u + 2u * 8388608u;   // 55,083,008
  int g = 1;
  if (ws_size >= need4) g = 4;
  else if (ws_size >= need2) g = 2;

  const float qscale = 0.03608439182435161f;  // 1/sqrt(768)

  convert_pack<<<dim3(3072), dim3(256), 0, stream>>>(x, xbp);
  transpose_pack_w<<<dim3(24, 24, 3), dim3(32, 8), 0, stream>>>(Wq, Wk, Wv, wtp);

  gemm_proj<<<dim3(576), dim3(512), 0, stream>>>(xbp, wtp, Qp, Kp, Vtp);

  for (int b0 = 0; b0 < 4; b0 += g) {
    int gb = 4 - b0 < g ? 4 - b0 : g;
    gemm_s_exp<<<dim3(8, 16, gb), dim3(512), 0, stream>>>(
        Qp + (long)b0 * 16 * 98304, Kp + (long)b0 * 16 * 98304, Pp, l_part, qscale);
    sum_l_inv<<<dim3(gb * 8), dim3(256), 0, stream>>>(l_part, l_inv, gb * 2048);
    gemm_pv<<<dim3(16, 6, gb), dim3(256), 0, stream>>>(
        Pp, Vtp + (long)b0 * 32 * GR, l_inv, out + (long)b0 * SU);
  }
}

// Round 4
// 191.914 us; speedup vs baseline: 1.1003x; 1.0525x over previous
//
#include <hip/hip_runtime.h>
#include <stdint.h>

// Self-attention: x[4,2048,768] fp32, W_q/W_k/W_v [768,768] fp32 -> out[4,2048,768] fp32.
//
// v9: fill + locality + fusion (cores held fixed from v8 for attribution).
//  - Row-sum fused into s_exp via global atomicAdd into l[4][2048] (memset once);
//    PV reads 1/l directly. sum_l_inv kernel + lpart/linv buffers deleted.
//  - Workspace re-layout: g=4 needs 71.34 MB (ladder falls back to g=2/1 safely).
//    At g=4: ONE s_exp launch (1024 blocks = 2/CU, 16 waves/CU) + ONE PV launch
//    (384 blocks = 1.5/CU).
//  - Bijective XCD-chunked block swizzle on s_exp (chunk = fixed z, 4 by, all bx:
//    per-XCD WS = Q 3.1 MB + K 0.8 MB < 4 MB L2) and PV (V-strip reuse).
//
// Packed layout: operand = [row-block r/128][it = k/64][16 KB chunk]; chunk =
// [p = k-octet 0..8][r 0..128][8 u16]. A 32-k piece = half-chunk = 4096 u16.

typedef unsigned short u16;
typedef unsigned int u32;

typedef __attribute__((ext_vector_type(4))) float f32x4;
typedef __attribute__((ext_vector_type(8))) __bf16 bf16x8;
typedef __attribute__((ext_vector_type(8))) short s16x8;
typedef __attribute__((ext_vector_type(8))) unsigned short us16x8;

template <class T> T&& declv();
template <typename T, typename V = void>
struct mfma_ok { static constexpr bool value = false; };
template <typename T>
struct mfma_ok<T, decltype((void)__builtin_amdgcn_mfma_f32_16x16x32_bf16(
                     declv<T>(), declv<T>(), declv<f32x4>(), 0, 0, 0))> {
  static constexpr bool value = true;
};
template <bool BF, bool S16> struct pick_frag { typedef us16x8 type; };
template <bool S16> struct pick_frag<true, S16> { typedef bf16x8 type; };
template <> struct pick_frag<false, true> { typedef s16x8 type; };
typedef typename pick_frag<mfma_ok<bf16x8>::value, mfma_ok<s16x8>::value>::type frag_t;

__device__ inline f32x4 mfma16x16x32(frag_t a, frag_t b, f32x4 c) {
  return __builtin_amdgcn_mfma_f32_16x16x32_bf16(a, b, c, 0, 0, 0);
}

#define AS3(p) ((__attribute__((address_space(3))) void*)(p))
#define AS1c(p) ((__attribute__((address_space(1))) void*)(const void*)(p))

__device__ inline u16 f2bf(float f) {
  union { float f; u32 u; } v; v.f = f;
  u32 r = v.u + 0x7fffu + ((v.u >> 16) & 1u);  // RNE
  return (u16)(r >> 16);
}

#define GR 8192        // u16 per it-chunk (16 KB)
#define BOFF4 8192     // u16 offset of B half of LDS (128^2 loop)

// =====================================================================
// 128x128 / 4-wave loop — kept for gemm_pv only.
// =====================================================================
__device__ inline void gemm_loop4(u16* smem, const u16* __restrict__ Ap,
                                  const u16* __restrict__ Bp, int nit,
                                  f32x4 acc[4][4])
{
  const int tid  = threadIdx.x;
  const int lane = tid & 63;
  const int wave = tid >> 6;
  const int quad = lane >> 4;
  const int l16  = lane & 15;
  const int wm   = (wave & 1) * 64;
  const int wn   = (wave >> 1) * 64;
  const int so   = wave * 2048;
  const int lo   = lane << 3;

#pragma unroll
  for (int i = 0; i < 4; i++)
#pragma unroll
    for (int j = 0; j < 4; j++) acc[i][j] = f32x4{0.f, 0.f, 0.f, 0.f};

  for (int it = 0; it < nit; ++it) {
    const long o = (long)it * GR;
    __syncthreads();
#pragma unroll
    for (int j = 0; j < 4; j++) {
      __builtin_amdgcn_global_load_lds(AS1c(Ap + o + so + j * 512 + lo),
                                       AS3(smem + so + j * 512), 16, 0, 0);
      __builtin_amdgcn_global_load_lds(AS1c(Bp + o + so + j * 512 + lo),
                                       AS3(smem + BOFF4 + so + j * 512), 16, 0, 0);
    }
    __syncthreads();

#pragma unroll
    for (int s = 0; s < 2; s++) {
      frag_t af[4], bf_[4];
#pragma unroll
      for (int mt = 0; mt < 4; mt++)
        af[mt] = *(const frag_t*)(&smem[(s * 4 + quad) * 1024 + (wm + mt * 16 + l16) * 8]);
#pragma unroll
      for (int nt = 0; nt < 4; nt++)
        bf_[nt] = *(const frag_t*)(&smem[BOFF4 + (s * 4 + quad) * 1024 + (wn + nt * 16 + l16) * 8]);
#pragma unroll
      for (int mt = 0; mt < 4; mt++)
#pragma unroll
        for (int nt = 0; nt < 4; nt++)
          acc[mt][nt] = mfma16x16x32(af[mt], bf_[nt], acc[mt][nt]);
    }
  }
}

// =====================================================================
// 256x128 / 8-wave / BK=32 / triple-buffered core (72 KiB LDS) — unchanged.
// =====================================================================
__device__ __forceinline__ void gemm128c_loop(u16* smem,
    const u16* __restrict__ A0, const u16* __restrict__ A1,
    const u16* __restrict__ B0, int nt32, f32x4 acc[4][4])
{
  const int tid   = threadIdx.x;
  const int lane  = tid & 63;
  const int wave  = tid >> 6;      // 0..7
  const int quad  = lane >> 4;
  const int l16   = lane & 15;
  const int waveM = wave >> 1;     // 0..3 (64-row strip)
  const int waveN = wave & 1;      // 0..1 (64-col strip)
  const int wch   = wave * 512;    // wave chunk within a 4096-u16 piece
  const int go    = tid * 8;       // per-lane global offset (u16)

#pragma unroll
  for (int i = 0; i < 4; i++)
#pragma unroll
    for (int j = 0; j < 4; j++) acc[i][j] = f32x4{0.f, 0.f, 0.f, 0.f};

#define STG3(T, BUF) do {                                                      \
    const long _p = (long)(T) * 4096;                                          \
    const int _b = (BUF) * 12288 + wch;                                        \
    __builtin_amdgcn_global_load_lds(AS1c(A0 + _p + go), AS3(smem + _b),       \
                                     16, 0, 0);                                \
    __builtin_amdgcn_global_load_lds(AS1c(A1 + _p + go), AS3(smem + _b + 4096),\
                                     16, 0, 0);                                \
    __builtin_amdgcn_global_load_lds(AS1c(B0 + _p + go), AS3(smem + _b + 8192),\
                                     16, 0, 0);                                \
  } while (0)

  // Prologue: stage tiles 0,1; wait tile 0 (3 newest pending).
  STG3(0, 0);
  STG3(1, 1);
  asm volatile("s_waitcnt vmcnt(3)" ::: "memory");
  __builtin_amdgcn_s_barrier();

  const int ablk = (waveM >> 1) * 4096;
  const int arow = ((waveM & 1) * 64 + l16) * 8;
  const int brow = (waveN * 64 + l16) * 8;

  int bc = 0;  // t % 3
  for (int t = 0; t < nt32; ++t) {
    const int bb = bc * 12288;
    frag_t af[4], bfr[4];
#pragma unroll
    for (int mt = 0; mt < 4; mt++)
      af[mt] = *(const frag_t*)(smem + bb + ablk + quad * 1024 + arow + mt * 128);
#pragma unroll
    for (int nt = 0; nt < 4; nt++)
      bfr[nt] = *(const frag_t*)(smem + bb + 8192 + quad * 1024 + brow + nt * 128);

    if (t + 2 < nt32) {
      const int sc = bc == 0 ? 2 : bc - 1;  // (t+2) % 3
      STG3(t + 2, sc);
    }
    __builtin_amdgcn_s_barrier();
    asm volatile("s_waitcnt lgkmcnt(0)" ::: "memory");
    __builtin_amdgcn_sched_barrier(0);
    __builtin_amdgcn_s_setprio(1);
#pragma unroll
    for (int mt = 0; mt < 4; mt++)
#pragma unroll
      for (int nt = 0; nt < 4; nt++)
        acc[mt][nt] = mfma16x16x32(af[mt], bfr[nt], acc[mt][nt]);
    __builtin_amdgcn_s_setprio(0);

    if (t + 3 <= nt32)      { asm volatile("s_waitcnt vmcnt(3)" ::: "memory"); }
    else if (t + 2 <= nt32) { asm volatile("s_waitcnt vmcnt(0)" ::: "memory"); }
    __builtin_amdgcn_s_barrier();
    bc = bc == 2 ? 0 : bc + 1;
  }
#undef STG3
}

// Packed bf16 epilogue for a 256x128 tile (unchanged).
__device__ __forceinline__ void epi_pack_rc(u16* smem, u16* __restrict__ dst0,
                                            u16* __restrict__ dst1, f32x4 acc[4][4])
{
  const int tid   = threadIdx.x;
  const int lane  = tid & 63;
  const int wave  = tid >> 6;
  const int quad  = lane >> 4;
  const int l16   = lane & 15;
  const int waveM = wave >> 1;
  const int waveN = wave & 1;

  __syncthreads();
  const int base = (waveM >> 1) * 16384 + waveN * 8192 + (l16 >> 3) * 1024 + (l16 & 7);
  const int rr0  = (waveM & 1) * 64 + quad * 4;
#pragma unroll
  for (int mt = 0; mt < 4; mt++)
#pragma unroll
    for (int nt = 0; nt < 4; nt++) {
#pragma unroll
      for (int i = 0; i < 4; i++)
        smem[base + nt * 2048 + (rr0 + mt * 16 + i) * 8] = f2bf(acc[mt][nt][i]);
    }
  __syncthreads();
#pragma unroll
  for (int k = 0; k < 4; k++) {
    const int idx = k * 4096 + tid * 8;
    *(uint4*)(dst0 + idx) = *(const uint4*)(smem + idx);
    *(uint4*)(dst1 + idx) = *(const uint4*)(smem + 16384 + idx);
  }
}

// Exp + packed + row-sum epilogue; row-sums accumulate ATOMICALLY into lG[row]
// (lG pre-offset to this block's z and 256-row window).
__device__ __forceinline__ void epi_exp_rc(u16* smem, u16* __restrict__ dst0,
                                           u16* __restrict__ dst1,
                                           float* __restrict__ lG,
                                           f32x4 acc[4][4], float qscale)
{
  const int tid   = threadIdx.x;
  const int lane  = tid & 63;
  const int wave  = tid >> 6;
  const int quad  = lane >> 4;
  const int l16   = lane & 15;
  const int waveM = wave >> 1;
  const int waveN = wave & 1;
  float* lrow = (float*)(smem + 32768);  // [256][2] floats (2 KB)

  __syncthreads();
  const int base = (waveM >> 1) * 16384 + waveN * 8192 + (l16 >> 3) * 1024 + (l16 & 7);
  const int rr0  = (waveM & 1) * 64 + quad * 4;
  float s[4][4];
#pragma unroll
  for (int mt = 0; mt < 4; mt++)
#pragma unroll
    for (int i = 0; i < 4; i++) s[mt][i] = 0.f;

#pragma unroll
  for (int mt = 0; mt < 4; mt++)
#pragma unroll
    for (int nt = 0; nt < 4; nt++) {
#pragma unroll
      for (int i = 0; i < 4; i++) {
        float ev = __expf(acc[mt][nt][i] * qscale);
        smem[base + nt * 2048 + (rr0 + mt * 16 + i) * 8] = f2bf(ev);
        s[mt][i] += ev;
      }
    }
#pragma unroll
  for (int mt = 0; mt < 4; mt++)
#pragma unroll
    for (int i = 0; i < 4; i++) {
      float v = s[mt][i];
      v += __shfl_xor(v, 1, 16);
      v += __shfl_xor(v, 2, 16);
      v += __shfl_xor(v, 4, 16);
      v += __shfl_xor(v, 8, 16);
      if (l16 == 0)
        lrow[(waveM * 64 + mt * 16 + quad * 4 + i) * 2 + waveN] = v;
    }
  __syncthreads();
#pragma unroll
  for (int k = 0; k < 4; k++) {
    const int idx = k * 4096 + tid * 8;
    *(uint4*)(dst0 + idx) = *(const uint4*)(smem + idx);
    *(uint4*)(dst1 + idx) = *(const uint4*)(smem + 16384 + idx);
  }
  if (tid < 256) atomicAdd(&lG[tid], lrow[tid * 2] + lrow[tid * 2 + 1]);
}

// =====================================================================
// Merged Q/K/V^T projection, 256x128 tiles: grid 576 (unchanged).
// =====================================================================
__global__ __launch_bounds__(512, 2)
void gemm_proj(const u16* __restrict__ xbp, const u16* __restrict__ wtp,
               u16* __restrict__ Qp, u16* __restrict__ Kp, u16* __restrict__ Vtp)
{
  __shared__ alignas(16) u16 smem[36864];
  f32x4 acc[4][4];
  const int x = blockIdx.x;
  const u16 *A0, *A1, *B0;
  u16 *d0, *d1;
  if (x < 384) {
    const int bx = x & 31, by = x >> 5;
    A0 = xbp + (long)(2 * bx) * 98304;  A1 = A0 + 98304;
    B0 = wtp + (long)by * 98304;
    d0 = (by < 6) ? Qp + (long)(2 * bx) * 98304 + (long)(2 * by) * GR
                  : Kp + (long)(2 * bx) * 98304 + (long)(2 * (by - 6)) * GR;
    d1 = d0 + 98304;
  } else {
    const int i = x - 384;
    const int bxv = i >> 6, byv = i & 63;
    A0 = wtp + (long)(12 + 2 * bxv) * 98304;  A1 = A0 + 98304;
    B0 = xbp + (long)byv * 98304;
    d0 = Vtp + (long)(2 * bxv) * 1048576 + (long)(2 * byv) * GR;
    d1 = d0 + 1048576;
  }
  gemm128c_loop(smem, A0, A1, B0, 24, acc);
  epi_pack_rc(smem, d0, d1, acc);
}

// =====================================================================
// S-GEMM + fused exp/atomic-row-sum, 256x128 tiles: grid (8,16,gb).
// XCD-chunked bijective swizzle: chunk = (fixed z, 4 consecutive by, all bx)
// -> per-XCD L2 working set = Q(batch) 3.1 MB + 4 K-blocks 0.8 MB < 4 MB.
// =====================================================================
__global__ __launch_bounds__(512, 2)
void gemm_s_exp(const u16* __restrict__ Qp, const u16* __restrict__ Kp,
                u16* __restrict__ Pp, float* __restrict__ l, float qscale)
{
  __shared__ alignas(16) u16 smem[36864];
  f32x4 acc[4][4];
  const int nb  = (int)gridDim.z << 7;           // 128 * gb  (divisible by 8)
  const int u   = (int)blockIdx.x + ((int)blockIdx.y << 3) + ((int)blockIdx.z << 7);
  const int cpx = nb >> 3;
  const int wg  = (u & 7) * cpx + (u >> 3);      // bijective chunked swizzle
  const int bx = wg & 7, by = (wg >> 3) & 15, z = wg >> 7;

  const u16* A0 = Qp + (long)(z * 16 + 2 * bx) * 98304;
  const u16* B0 = Kp + (long)(z * 16 + by) * 98304;
  gemm128c_loop(smem, A0, A0 + 98304, B0, 24, acc);
  u16* d0 = Pp + (long)z * 4194304 + (long)(2 * bx) * 262144 + (long)(2 * by) * GR;
  epi_exp_rc(smem, d0, d0 + 262144, l + z * 2048 + bx * 256, acc, qscale);
}

// =====================================================================
// One-shot PV (K=2048, NIT=32), grid (16,6,gb); reads 1/l directly.
// XCD-chunked swizzle (bx-fastest order): V-strip reuse within XCD.
// =====================================================================
__global__ __launch_bounds__(256)
void gemm_pv(const u16* __restrict__ Pp, const u16* __restrict__ Vtp_off,
             const float* __restrict__ l, float* __restrict__ out)
{
  __shared__ alignas(16) u16 smem[16384];
  f32x4 acc[4][4];
  const long SU = 2048L * 768;
  const int nb  = 96 * (int)gridDim.z;           // 96*gb (divisible by 8)
  const int u   = (int)blockIdx.x + ((int)blockIdx.y << 4) + (int)blockIdx.z * 96;
  const int cpx = nb >> 3;
  const int wg  = (u & 7) * cpx + (u >> 3);
  const int bx = wg & 15, by = (wg >> 4) % 6, z = wg / 96;

  gemm_loop4(smem,
             Pp + (long)z * 4194304 + (long)bx * 262144,
             Vtp_off + (long)by * 1048576 + (long)(z * 32) * GR,
             32, acc);

  __syncthreads();
  float* lsl = (float*)smem;
  const int tid = threadIdx.x;
  if (tid < 128) lsl[tid] = 1.0f / l[z * 2048 + bx * 128 + tid];
  __syncthreads();

  const int lane = tid & 63;
  const int wave = tid >> 6;
  const int quad = lane >> 4;
  const int l16  = lane & 15;
  const int wm   = (wave & 1) * 64;
  const int wn   = (wave >> 1) * 64;
  float* C = out + (long)z * SU;
#pragma unroll
  for (int mt = 0; mt < 4; mt++)
#pragma unroll
    for (int nt = 0; nt < 4; nt++) {
      const int r0 = bx * 128 + wm + mt * 16 + quad * 4;
      const int lr = wm + mt * 16 + quad * 4;
      const int cc = by * 128 + wn + nt * 16 + l16;
#pragma unroll
      for (int i = 0; i < 4; i++)
        C[(long)(r0 + i) * 768 + cc] = acc[mt][nt][i] * lsl[lr + i];
    }
}

// =====================================================================
// x [8192 x 768] fp32 -> packed bf16 [64 blocks][12 its]. 8 elems/thread.
// =====================================================================
__global__ __launch_bounds__(256)
void convert_pack(const float* __restrict__ x, u16* __restrict__ xbp)
{
  const int tg = blockIdx.x * 256 + threadIdx.x;
  const int m = tg / 96;
  const int g = tg - m * 96;
  const float4* px = (const float4*)(x + (long)m * 768 + g * 8);
  float4 a = px[0], b = px[1];
  uint4 u;
  u.x = (u32)f2bf(a.x) | ((u32)f2bf(a.y) << 16);
  u.y = (u32)f2bf(a.z) | ((u32)f2bf(a.w) << 16);
  u.z = (u32)f2bf(b.x) | ((u32)f2bf(b.y) << 16);
  u.w = (u32)f2bf(b.z) | ((u32)f2bf(b.w) << 16);
  const long addr = (long)(m >> 7) * 98304 + (g >> 3) * GR + (g & 7) * 1024 + (m & 127) * 8;
  *(uint4*)(xbp + addr) = u;
}

// =====================================================================
// W [768x768] fp32 -> W^T packed bf16 into wtp blocks z*6 .. z*6+5.
// =====================================================================
__global__ __launch_bounds__(256)
void transpose_pack_w(const float* __restrict__ W0, const float* __restrict__ W1,
                      const float* __restrict__ W2, u16* __restrict__ wtp)
{
  const float* W = blockIdx.z == 0 ? W0 : (blockIdx.z == 1 ? W1 : W2);
  __shared__ u16 tile[32][33];
  const int bx = blockIdx.x * 32;
  const int by = blockIdx.y * 32;
  const int tx = threadIdx.x, ty = threadIdx.y;
#pragma unroll
  for (int i = 0; i < 32; i += 8)
    tile[ty + i][tx] = f2bf(W[(long)(by + ty + i) * 768 + bx + tx]);
  __syncthreads();
  const int t = ty * 32 + tx;
  if (t < 128) {
    const int ul = t >> 2, dg = t & 3;
    const int u = bx + ul, d0 = by + dg * 8;
    uint4 o;
    u32 w_[4];
#pragma unroll
    for (int i = 0; i < 4; i++)
      w_[i] = (u32)tile[dg * 8 + 2 * i][ul] | ((u32)tile[dg * 8 + 2 * i + 1][ul] << 16);
    o.x = w_[0]; o.y = w_[1]; o.z = w_[2]; o.w = w_[3];
    const long addr = (long)(blockIdx.z * 6 + (u >> 7)) * 98304
                    + (d0 >> 6) * GR + ((d0 >> 3) & 7) * 1024 + (u & 127) * 8;
    *(uint4*)(wtp + addr) = o;
  }
}

// =====================================================================
extern "C" void kernel_launch(void* const* d_in, const int* in_sizes, int n_in,
                              void* d_out, int out_size, void* d_ws, size_t ws_size,
                              hipStream_t stream) {
  (void)in_sizes; (void)n_in; (void)out_size;
  const float* x  = (const float*)d_in[0];
  const float* Wq = (const float*)d_in[1];
  const float* Wk = (const float*)d_in[2];
  const float* Wv = (const float*)d_in[3];
  float* out = (float*)d_out;

  const long SU = 2048L * 768;

  // Layout (byte offsets from ws base):
  //   [Qp 12.58M][Kp 12.58M][Vtp 12.58M]                end 37,748,736
  //   [Pp g*8.39M]                                      (overlaps xbp+wtp region)
  //   [l  32 KB]                                        after Pp
  //   xbp @ 37,748,736 (12.58M), wtp @ 50,331,648 (3.54M) — dead after proj.
  u16* Qp  = (u16*)d_ws;
  u16* Kp  = Qp + 6291456;
  u16* Vtp = Kp + 6291456;
  u16* xbp = (u16*)((char*)d_ws + 37748736);
  u16* wtp = (u16*)((char*)d_ws + 50331648);
  u16* Pp  = xbp;  // P overlaps xbp+wtp (dead after proj)

  const size_t need4 = 37748736u + 4u * 8388608u + 32768u;  // 71,335,936
  const size_t need2 = 37748736u + 2u * 8388608u + 32768u;  // 54,591,488
  int g = 1;
  if (ws_size >= need4) g = 4;
  else if (ws_size >= need2) g = 2;

  float* l = (float*)((char*)d_ws + 37748736 + (size_t)g * 8388608);

  const float qscale = 0.03608439182435161f;  // 1/sqrt(768)

  convert_pack<<<dim3(3072), dim3(256), 0, stream>>>(x, xbp);
  transpose_pack_w<<<dim3(24, 24, 3), dim3(32, 8), 0, stream>>>(Wq, Wk, Wv, wtp);

  gemm_proj<<<dim3(576), dim3(512), 0, stream>>>(xbp, wtp, Qp, Kp, Vtp);

  // Zero the atomic row-sum buffer (covers all 4 batches).
  hipMemsetAsync(l, 0, 4 * 2048 * sizeof(float), stream);

  for (int b0 = 0; b0 < 4; b0 += g) {
    int gb = 4 - b0 < g ? 4 - b0 : g;
    gemm_s_exp<<<dim3(8, 16, gb), dim3(512), 0, stream>>>(
        Qp + (long)b0 * 16 * 98304, Kp + (long)b0 * 16 * 98304, Pp,
        l + (long)b0 * 2048, qscale);
    gemm_pv<<<dim3(16, 6, gb), dim3(256), 0, stream>>>(
        Pp, Vtp + (long)b0 * 32 * GR, l + (long)b0 * 2048, out + (long)b0 * SU);
  }
}